// Round 4
// baseline (10418.842 us; speedup 1.0000x reference)
//
#include <hip/hip_runtime.h>
#include <hip/hip_bf16.h>

// GRU: SEQ=512, B=64, I=512, H=1024, O=512
#define SEQL 512
#define BATCH 64
#define INF 512
#define HID 1024
#define OUTF 512
#define SB (SEQL*BATCH)

typedef __attribute__((ext_vector_type(8))) __bf16 bf16x8;
typedef __attribute__((ext_vector_type(4))) float f32x4;

__device__ inline bf16x8 ld_bf8(const void* p) { return *reinterpret_cast<const bf16x8*>(p); }
__device__ inline unsigned short f2bf(float f) { __bf16 b = (__bf16)f; return __builtin_bit_cast(unsigned short, b); }

// Coherent (IF-level) 16B load: two relaxed agent-scope 64-bit atomic loads.
// Emits global_load_dwordx2 with sc0/sc1 (bypass L1+L2, read from Infinity Cache) and
// NO cache-maintenance instructions (that's the point: no buffer_inv per poll/load).
__device__ inline bf16x8 ld_bf8c(const void* p) {
    union { unsigned long long q[2]; bf16x8 v; } u;
    const unsigned long long* qp = (const unsigned long long*)p;
    u.q[0] = __hip_atomic_load(qp,     __ATOMIC_RELAXED, __HIP_MEMORY_SCOPE_AGENT);
    u.q[1] = __hip_atomic_load(qp + 1, __ATOMIC_RELAXED, __HIP_MEMORY_SCOPE_AGENT);
    return u.v;
}
// Coherent 16-bit store (write-through to IF; completion tracked by vmcnt).
__device__ inline void st_u16c(unsigned short* p, unsigned short v) {
    __hip_atomic_store(p, v, __ATOMIC_RELAXED, __HIP_MEMORY_SCOPE_AGENT);
}

// ---------------- prep kernels ----------------
__global__ void cvt_f32_bf16(const float* __restrict__ src, unsigned short* __restrict__ dst, int n) {
    int i = (blockIdx.x * blockDim.x + threadIdx.x) * 4;
    if (i < n) {
        float4 v = *reinterpret_cast<const float4*>(src + i);
        ushort4 o = make_ushort4(f2bf(v.x), f2bf(v.y), f2bf(v.z), f2bf(v.w));
        *reinterpret_cast<ushort4*>(dst + i) = o;
    }
}

__global__ void make_bias2(const float* bxz, const float* bhz, const float* bxr,
                           const float* bhr, float* bias2) {
    int i = blockIdx.x * blockDim.x + threadIdx.x;
    if (i < HID) bias2[i] = bxz[i] + bhz[i];
    else if (i < 2*HID) bias2[i] = bxr[i-HID] + bhr[i-HID];
}

__global__ void fail_sentinel(float* o) { o[0] = 1e9f; }

// ---------------- tiled NT GEMM: C[M,N] = A[M,K] * B[N,K]^T + bias (fp32 out) ----------------
__global__ __launch_bounds__(256, 2) void gemm_nt_f32(
        const unsigned short* __restrict__ A, int lda,
        const unsigned short* __restrict__ Bw, int ldb,
        const float* __restrict__ bias,
        float* __restrict__ Cf, int N, int K) {
    __shared__ __align__(16) char lds[32768];
    const int tid = threadIdx.x;
    const int ntn = N >> 7;
    const int bm = blockIdx.x / ntn, bn = blockIdx.x % ntn;
    const int rowbase = bm << 7, colbase = bn << 7;
    const int wave = tid >> 6, lane = tid & 63, lo = lane & 15, hi = lane >> 4;
    const int vm = wave >> 1, vn = wave & 1;

    auto stage = [&](int abase, int k0) {
        #pragma unroll
        for (int i = 0; i < 2; i++) {
            int linear = i * 256 + tid;
            int r = linear >> 2, s = linear & 3;
            int c = (s - (r >> 1)) & 3;
            const unsigned short* ga = A + (size_t)(rowbase + r) * lda + k0 + c * 8;
            const unsigned short* gb = Bw + (size_t)(colbase + r) * ldb + k0 + c * 8;
            __builtin_amdgcn_global_load_lds(
                (const __attribute__((address_space(1))) unsigned int*)ga,
                (__attribute__((address_space(3))) unsigned int*)(lds + abase + linear * 16), 16, 0, 0);
            __builtin_amdgcn_global_load_lds(
                (const __attribute__((address_space(1))) unsigned int*)gb,
                (__attribute__((address_space(3))) unsigned int*)(lds + 16384 + abase + linear * 16), 16, 0, 0);
        }
    };

    f32x4 acc[4][4] = {};
    const int nk = K >> 5;
    stage(0, 0);
    for (int kt = 0; kt < nk; kt++) {
        __syncthreads();
        if (kt + 1 < nk) stage(((kt + 1) & 1) * 8192, (kt + 1) << 5);
        const char* cA = lds + (kt & 1) * 8192;
        const char* cB = lds + 16384 + (kt & 1) * 8192;
        bf16x8 af[4], bfr[4];
        #pragma unroll
        for (int m = 0; m < 4; m++) {
            int r = vm * 64 + m * 16 + lo;
            af[m] = ld_bf8(cA + r * 64 + 16 * ((hi + (r >> 1)) & 3));
        }
        #pragma unroll
        for (int n = 0; n < 4; n++) {
            int r = vn * 64 + n * 16 + lo;
            bfr[n] = ld_bf8(cB + r * 64 + 16 * ((hi + (r >> 1)) & 3));
        }
        #pragma unroll
        for (int m = 0; m < 4; m++)
            #pragma unroll
            for (int n = 0; n < 4; n++)
                acc[m][n] = __builtin_amdgcn_mfma_f32_16x16x32_bf16(af[m], bfr[n], acc[m][n], 0, 0, 0);
        __syncthreads();
    }

    #pragma unroll
    for (int n = 0; n < 4; n++) {
        int col = colbase + vn * 64 + n * 16 + lo;
        float bv = bias[col];
        #pragma unroll
        for (int m = 0; m < 4; m++)
            #pragma unroll
            for (int r = 0; r < 4; r++) {
                int row = rowbase + vm * 64 + m * 16 + hi * 4 + r;
                Cf[(size_t)row * N + col] = acc[m][n][r] + bv;
            }
    }
}

// ---------------- persistent GRU scan (fence-free sync, pinned weights) ----------------
// 128 WGs x 192 threads. wid: rb = wid>>6 (32 batch rows), cb = wid&63 (16 h-cols).
// The two rb-groups are INDEPENDENT scans: separate barrier counters (cnt + rb*32).
// Wave g in {0=z,1=r,2=hcand}: [Wh_g | Wx_g] slice pinned in 192 VGPRs via asm "+v".
// h exchange goes through the Infinity Cache: relaxed agent-scope atomic stores/loads
// (sc0/sc1 bypass of L1/L2) -> no buffer_wbl2/buffer_inv anywhere in the loop.
// x-side MFMAs for step t+1 overlap the barrier wait.
__global__ __launch_bounds__(192, 1) void gru_scan(
        const unsigned short* __restrict__ Whc,   // [3][H][H]  (z,r,h)
        const unsigned short* __restrict__ Wxc,   // [3][H][I]  (z,r,h)
        const unsigned short* __restrict__ xbf,   // [S*B][I]
        unsigned short* __restrict__ hs,          // [S+1][B][H]
        const float* __restrict__ bias2,          // [2H]: bxz+bhz | bxr+bhr
        const float* __restrict__ bxh,
        const float* __restrict__ bhh,
        unsigned int* cnt) {
    const int wid = blockIdx.x;
    const int rb = wid >> 6;          // 0..1  (independent batch-row group)
    const int cb = wid & 63;          // 0..63
    const int g = threadIdx.x / 64;   // gate/wave
    const int lane = threadIdx.x & 63, lo = lane & 15, hi = lane >> 4;

    __shared__ f32x4 Px[3][2][64];    // [0]=r-pre, [1]=hcand h-part, [2]=hcand x-part

    const int col = cb * 16 + lo;
    bf16x8 wh[32], wx[16];
    {
        const unsigned short* p = Whc + ((size_t)g * HID + col) * HID + hi * 8;
        #pragma unroll
        for (int kb = 0; kb < 32; kb++) wh[kb] = ld_bf8(p + kb * 32);
        const unsigned short* q = Wxc + ((size_t)g * HID + col) * INF + hi * 8;
        #pragma unroll
        for (int kb = 0; kb < 16; kb++) wx[kb] = ld_bf8(q + kb * 32);
    }
    // Pin the fragments in VGPRs: asm output is opaque -> compiler cannot sink the
    // loads back into the loop (round-3 failure: VGPR_Count=156 < 192 needed).
    #pragma unroll
    for (int kb = 0; kb < 32; kb++) asm volatile("" : "+v"(wh[kb]));
    #pragma unroll
    for (int kb = 0; kb < 16; kb++) asm volatile("" : "+v"(wx[kb]));

    const float bzv  = bias2[col];
    const float brv  = bias2[HID + col];
    const float bxhv = bxh[col];
    const float bhhv = bhh[col];
    float hst[2][4] = {};             // fp32 state: row = 32rb+16m+4hi+r, col
    unsigned int* my_cnt = cnt + rb * 32;   // 128 B apart -> no false sharing

    // x-side preacts for t=0 (plain cached loads; xbf is read-only)
    f32x4 ax0 = {0,0,0,0}, ax1 = {0,0,0,0};
    {
        const unsigned short* x0p = xbf + ((size_t)(rb * 32 + lo)) * INF + hi * 8;
        #pragma unroll
        for (int kb = 0; kb < 16; kb++) {
            bf16x8 a0 = ld_bf8(x0p + kb * 32);
            bf16x8 a1 = ld_bf8(x0p + 16 * INF + kb * 32);
            ax0 = __builtin_amdgcn_mfma_f32_16x16x32_bf16(a0, wx[kb], ax0, 0, 0, 0);
            ax1 = __builtin_amdgcn_mfma_f32_16x16x32_bf16(a1, wx[kb], ax1, 0, 0, 0);
        }
    }

    for (int t = 0; t < SEQL; t++) {
        // --- h-side preacts (coherent loads from IF); t=0: h0 == 0, skip ---
        f32x4 ah0 = {0,0,0,0}, ah1 = {0,0,0,0};
        if (t > 0) {
            const unsigned short* a0p = hs + (size_t)t * (BATCH * HID)
                                      + (size_t)(rb * 32 + lo) * HID + hi * 8;
            #pragma unroll
            for (int kb = 0; kb < 32; kb++) {
                bf16x8 a0 = ld_bf8c(a0p + kb * 32);
                bf16x8 a1 = ld_bf8c(a0p + 16 * HID + kb * 32);
                ah0 = __builtin_amdgcn_mfma_f32_16x16x32_bf16(a0, wh[kb], ah0, 0, 0, 0);
                ah1 = __builtin_amdgcn_mfma_f32_16x16x32_bf16(a1, wh[kb], ah1, 0, 0, 0);
            }
        }

        // --- exchange r-pre and both hcand parts via LDS ---
        if (g == 1) {
            f32x4 v0, v1;
            #pragma unroll
            for (int r = 0; r < 4; r++) { v0[r] = ah0[r] + ax0[r] + brv; v1[r] = ah1[r] + ax1[r] + brv; }
            Px[0][0][lane] = v0; Px[0][1][lane] = v1;
        } else if (g == 2) {
            f32x4 v0, v1, w0, w1;
            #pragma unroll
            for (int r = 0; r < 4; r++) {
                v0[r] = ah0[r] + bhhv; v1[r] = ah1[r] + bhhv;
                w0[r] = ax0[r] + bxhv; w1[r] = ax1[r] + bxhv;
            }
            Px[1][0][lane] = v0; Px[1][1][lane] = v1;
            Px[2][0][lane] = w0; Px[2][1][lane] = w1;
        }
        __syncthreads();

        // --- finalize by wave 0; h stores write through to IF ---
        if (g == 0) {
            unsigned short* hdst = hs + (size_t)(t + 1) * (BATCH * HID);
            f32x4 az[2];
            #pragma unroll
            for (int r = 0; r < 4; r++) { az[0][r] = ah0[r] + ax0[r] + bzv; az[1][r] = ah1[r] + ax1[r] + bzv; }
            f32x4 pr[2] = { Px[0][0][lane], Px[0][1][lane] };
            f32x4 ph[2] = { Px[1][0][lane], Px[1][1][lane] };
            f32x4 px[2] = { Px[2][0][lane], Px[2][1][lane] };
            #pragma unroll
            for (int m = 0; m < 2; m++)
                #pragma unroll
                for (int r = 0; r < 4; r++) {
                    float z  = 1.f / (1.f + __expf(-az[m][r]));
                    float rr = 1.f / (1.f + __expf(-pr[m][r]));
                    float hc = tanhf(px[m][r] + rr * ph[m][r]);
                    hst[m][r] = (1.f - z) * hst[m][r] + z * hc;
                    st_u16c(hdst + (size_t)(rb * 32 + m * 16 + hi * 4 + r) * HID + col, f2bf(hst[m][r]));
                }
        }

        // --- fence-free group barrier ---
        __syncthreads();               // drains vmcnt(0): all h stores are at the IF before the flag moves
        if (threadIdx.x == 0)
            __hip_atomic_fetch_add(my_cnt, 1u, __ATOMIC_RELAXED, __HIP_MEMORY_SCOPE_AGENT);

        // overlap the barrier wait with next step's x-side preacts (h-independent)
        f32x4 nax0 = {0,0,0,0}, nax1 = {0,0,0,0};
        if (t + 1 < SEQL) {
            const unsigned short* x1p = xbf + ((size_t)(t + 1) * BATCH + rb * 32 + lo) * INF + hi * 8;
            #pragma unroll
            for (int kb = 0; kb < 16; kb++) {
                bf16x8 a0 = ld_bf8(x1p + kb * 32);
                bf16x8 a1 = ld_bf8(x1p + 16 * INF + kb * 32);
                nax0 = __builtin_amdgcn_mfma_f32_16x16x32_bf16(a0, wx[kb], nax0, 0, 0, 0);
                nax1 = __builtin_amdgcn_mfma_f32_16x16x32_bf16(a1, wx[kb], nax1, 0, 0, 0);
            }
        }

        if (threadIdx.x == 0) {
            unsigned int tgt = (unsigned int)(t + 1) * 64u;   // 64 WGs per rb-group
            while (__hip_atomic_load(my_cnt, __ATOMIC_RELAXED, __HIP_MEMORY_SCOPE_AGENT) < tgt)
                __builtin_amdgcn_s_sleep(2);
        }
        __syncthreads();
        ax0 = nax0; ax1 = nax1;
    }
}

// ---------------- host ----------------
extern "C" void kernel_launch(void* const* d_in, const int* in_sizes, int n_in,
                              void* d_out, int out_size, void* d_ws, size_t ws_size,
                              hipStream_t stream) {
    const float* x   = (const float*)d_in[0];
    const float* Wxz = (const float*)d_in[1];
    const float* bxz = (const float*)d_in[2];
    const float* Whz = (const float*)d_in[3];
    const float* bhz = (const float*)d_in[4];
    const float* Wxr = (const float*)d_in[5];
    const float* bxr = (const float*)d_in[6];
    const float* Whr = (const float*)d_in[7];
    const float* bhr = (const float*)d_in[8];
    const float* Wxh = (const float*)d_in[9];
    const float* bxh = (const float*)d_in[10];
    const float* Whh = (const float*)d_in[11];
    const float* bhh = (const float*)d_in[12];
    const float* Why = (const float*)d_in[13];
    const float* bhy = (const float*)d_in[14];

    char* ws = (char*)d_ws;
    size_t off = 0;
    auto alloc = [&](size_t bytes) { char* p = ws + off; off += (bytes + 255) & ~(size_t)255; return p; };
    unsigned short* Whc   = (unsigned short*)alloc((size_t)3 * HID * HID * 2);   // 6.3 MB
    unsigned short* Wxc   = (unsigned short*)alloc((size_t)3 * HID * INF * 2);   // 3.1 MB
    unsigned short* Whyb  = (unsigned short*)alloc((size_t)OUTF * HID * 2);      // 1.0 MB
    float*          bias2 = (float*)alloc((size_t)2 * HID * 4);
    unsigned short* hsbuf = (unsigned short*)alloc((size_t)(SEQL + 1) * BATCH * HID * 2); // 67.2 MB
    unsigned int*   cnt   = (unsigned int*)alloc(256);
    unsigned short* x_bf  = (unsigned short*)d_out;  // dead region until the final GEMM

    if (off > ws_size) {
        fail_sentinel<<<dim3(1), dim3(1), 0, stream>>>((float*)d_out);
        return;
    }

    auto cvt = [&](const float* s, unsigned short* d, size_t n) {
        cvt_f32_bf16<<<dim3((unsigned)((n / 4 + 255) / 256)), dim3(256), 0, stream>>>(s, d, (int)n);
    };
    cvt(x, x_bf, (size_t)SB * INF);
    cvt(Whz, Whc, (size_t)HID * HID);
    cvt(Whr, Whc + (size_t)HID * HID, (size_t)HID * HID);
    cvt(Whh, Whc + (size_t)2 * HID * HID, (size_t)HID * HID);
    cvt(Wxz, Wxc, (size_t)HID * INF);
    cvt(Wxr, Wxc + (size_t)HID * INF, (size_t)HID * INF);
    cvt(Wxh, Wxc + (size_t)2 * HID * INF, (size_t)HID * INF);
    cvt(Why, Whyb, (size_t)OUTF * HID);
    make_bias2<<<dim3(8), dim3(256), 0, stream>>>(bxz, bhz, bxr, bhr, bias2);
    (void)hipMemsetAsync(cnt, 0, 256, stream);   // both group counters; kernel-boundary flush makes it IF-visible

    // scan: 128 WGs on 256 CUs -> co-resident; barrier is per-rb-group (64 WGs each)
    gru_scan<<<dim3(128), dim3(192), 0, stream>>>(Whc, Wxc, x_bf, hsbuf, bias2, bxh, bhh, cnt);

    // out[SB, O] = hs[1..512] @ Why^T + bhy  (overwrites x_bf region; x_bf is dead here)
    gemm_nt_f32<<<dim3((SB / 128) * (OUTF / 128)), dim3(256), 0, stream>>>(
        hsbuf + (size_t)BATCH * HID, HID, Whyb, HID, bhy, (float*)d_out, OUTF, HID);
}

// Round 5
// 8258.969 us; speedup vs baseline: 1.2615x; 1.2615x over previous
//
#include <hip/hip_runtime.h>
#include <hip/hip_bf16.h>

// GRU: SEQ=512, B=64, I=512, H=1024, O=512
#define SEQL 512
#define BATCH 64
#define INF 512
#define HID 1024
#define OUTF 512
#define SB (SEQL*BATCH)
#define BH (BATCH*HID)

typedef __attribute__((ext_vector_type(8))) __bf16 bf16x8;
typedef __attribute__((ext_vector_type(4))) float f32x4;

__device__ inline bf16x8 ld_bf8(const void* p) { return *reinterpret_cast<const bf16x8*>(p); }
__device__ inline unsigned short f2bf(float f) { __bf16 b = (__bf16)f; return __builtin_bit_cast(unsigned short, b); }

// Coherent (IF-level) 16B load as two relaxed agent-scope 8B atomic loads:
// sc0/sc1 bypass of L1/L2, no cache-maintenance ops. Relaxed => freely schedulable
// (only data deps order them), which is what lets them pipeline deeply.
__device__ inline bf16x8 ld_bf8c(const void* p) {
    union { unsigned long long q[2]; bf16x8 v; } u;
    const unsigned long long* qp = (const unsigned long long*)p;
    u.q[0] = __hip_atomic_load(qp,     __ATOMIC_RELAXED, __HIP_MEMORY_SCOPE_AGENT);
    u.q[1] = __hip_atomic_load(qp + 1, __ATOMIC_RELAXED, __HIP_MEMORY_SCOPE_AGENT);
    return u.v;
}
__device__ inline void st_u16c(unsigned short* p, unsigned short v) {
    __hip_atomic_store(p, v, __ATOMIC_RELAXED, __HIP_MEMORY_SCOPE_AGENT);
}

// ---------------- prep kernels ----------------
__global__ void cvt_f32_bf16(const float* __restrict__ src, unsigned short* __restrict__ dst, int n) {
    int i = (blockIdx.x * blockDim.x + threadIdx.x) * 4;
    if (i < n) {
        float4 v = *reinterpret_cast<const float4*>(src + i);
        ushort4 o = make_ushort4(f2bf(v.x), f2bf(v.y), f2bf(v.z), f2bf(v.w));
        *reinterpret_cast<ushort4*>(dst + i) = o;
    }
}

__global__ void make_bias2(const float* bxz, const float* bhz, const float* bxr,
                           const float* bhr, float* bias2) {
    int i = blockIdx.x * blockDim.x + threadIdx.x;
    if (i < HID) bias2[i] = bxz[i] + bhz[i];
    else if (i < 2*HID) bias2[i] = bxr[i-HID] + bhr[i-HID];
}

__global__ void fail_sentinel(float* o) { o[0] = 1e9f; }

// ---------------- tiled NT GEMM (unchanged, validated) ----------------
__global__ __launch_bounds__(256, 2) void gemm_nt_f32(
        const unsigned short* __restrict__ A, int lda,
        const unsigned short* __restrict__ Bw, int ldb,
        const float* __restrict__ bias,
        float* __restrict__ Cf, int N, int K) {
    __shared__ __align__(16) char lds[32768];
    const int tid = threadIdx.x;
    const int ntn = N >> 7;
    const int bm = blockIdx.x / ntn, bn = blockIdx.x % ntn;
    const int rowbase = bm << 7, colbase = bn << 7;
    const int wave = tid >> 6, lane = tid & 63, lo = lane & 15, hi = lane >> 4;
    const int vm = wave >> 1, vn = wave & 1;

    auto stage = [&](int abase, int k0) {
        #pragma unroll
        for (int i = 0; i < 2; i++) {
            int linear = i * 256 + tid;
            int r = linear >> 2, s = linear & 3;
            int c = (s - (r >> 1)) & 3;
            const unsigned short* ga = A + (size_t)(rowbase + r) * lda + k0 + c * 8;
            const unsigned short* gb = Bw + (size_t)(colbase + r) * ldb + k0 + c * 8;
            __builtin_amdgcn_global_load_lds(
                (const __attribute__((address_space(1))) unsigned int*)ga,
                (__attribute__((address_space(3))) unsigned int*)(lds + abase + linear * 16), 16, 0, 0);
            __builtin_amdgcn_global_load_lds(
                (const __attribute__((address_space(1))) unsigned int*)gb,
                (__attribute__((address_space(3))) unsigned int*)(lds + 16384 + abase + linear * 16), 16, 0, 0);
        }
    };

    f32x4 acc[4][4] = {};
    const int nk = K >> 5;
    stage(0, 0);
    for (int kt = 0; kt < nk; kt++) {
        __syncthreads();
        if (kt + 1 < nk) stage(((kt + 1) & 1) * 8192, (kt + 1) << 5);
        const char* cA = lds + (kt & 1) * 8192;
        const char* cB = lds + 16384 + (kt & 1) * 8192;
        bf16x8 af[4], bfr[4];
        #pragma unroll
        for (int m = 0; m < 4; m++) {
            int r = vm * 64 + m * 16 + lo;
            af[m] = ld_bf8(cA + r * 64 + 16 * ((hi + (r >> 1)) & 3));
        }
        #pragma unroll
        for (int n = 0; n < 4; n++) {
            int r = vn * 64 + n * 16 + lo;
            bfr[n] = ld_bf8(cB + r * 64 + 16 * ((hi + (r >> 1)) & 3));
        }
        #pragma unroll
        for (int m = 0; m < 4; m++)
            #pragma unroll
            for (int n = 0; n < 4; n++)
                acc[m][n] = __builtin_amdgcn_mfma_f32_16x16x32_bf16(af[m], bfr[n], acc[m][n], 0, 0, 0);
        __syncthreads();
    }

    #pragma unroll
    for (int n = 0; n < 4; n++) {
        int col = colbase + vn * 64 + n * 16 + lo;
        float bv = bias[col];
        #pragma unroll
        for (int m = 0; m < 4; m++)
            #pragma unroll
            for (int r = 0; r < 4; r++) {
                int row = rowbase + vm * 64 + m * 16 + hi * 4 + r;
                Cf[(size_t)row * N + col] = acc[m][n][r] + bv;
            }
    }
}

// ---------------- persistent GRU scan: weights in LDS, pipelined h-loads ----------------
// 128 WGs x 192 threads; rb = wid>>6 (32 batch rows), cb = wid&63 (16 h-cols); wave g = gate.
// LDS: [0,144K) weight frags (gate g at g*48K: wh frag kb at kb*1024+lane*16, wx at +32K),
//      [144K,150K) Px exchange. 150 KB static => 1 WG/CU, so the allocator has the full
//      512-VGPR budget for in-flight h-loads (round 3/4 failure: VGPR=156, serialized loads).
// Per step: h-phase = 4 chunks x 8 kfrags, issued 2 chunks ahead (named bufs, static idx).
// Barrier: wave0 drains own h-stores (vmcnt 0) -> thread0 relaxed add -> ALL waves poll.
// Safety: waves pass poll(t) only after own WG's wave0 added, which is after its Px reads.
__global__ __launch_bounds__(192, 1) void gru_scan(
        const unsigned short* __restrict__ Whc,   // [3][H][H]
        const unsigned short* __restrict__ Wxc,   // [3][H][I]
        const unsigned short* __restrict__ xbf,   // [S*B][I]
        unsigned short* __restrict__ hs,          // [S+1][B][H]
        const float* __restrict__ bias2,          // [2H]
        const float* __restrict__ bxh,
        const float* __restrict__ bhh,
        unsigned int* cnt) {
    __shared__ __align__(16) char lds[153600];
    const int wid = blockIdx.x;
    const int rb = wid >> 6;
    const int cb = wid & 63;
    const int g = threadIdx.x / 64;
    const int lane = threadIdx.x & 63, lo = lane & 15, hi = lane >> 4;
    const int col = cb * 16 + lo;
    char* whl = lds + g * 49152;          // 32 wh frags
    char* wxl = whl + 32768;              // 16 wx frags
    f32x4* Px = (f32x4*)(lds + 147456);   // [3][2][64]

    // ---- stage this WG's weight slices into LDS (once) ----
    {
        const unsigned short* ph = Whc + ((size_t)g * HID + col) * HID + hi * 8;
        #pragma unroll
        for (int kb = 0; kb < 32; kb++)
            __builtin_amdgcn_global_load_lds(
                (const __attribute__((address_space(1))) unsigned int*)(ph + kb * 32),
                (__attribute__((address_space(3))) unsigned int*)(whl + kb * 1024 + lane * 16), 16, 0, 0);
        const unsigned short* pxw = Wxc + ((size_t)g * HID + col) * INF + hi * 8;
        #pragma unroll
        for (int kb = 0; kb < 16; kb++)
            __builtin_amdgcn_global_load_lds(
                (const __attribute__((address_space(1))) unsigned int*)(pxw + kb * 32),
                (__attribute__((address_space(3))) unsigned int*)(wxl + kb * 1024 + lane * 16), 16, 0, 0);
    }
    __syncthreads();

    const float bzv  = bias2[col];
    const float brv  = bias2[HID + col];
    const float bxhv = bxh[col];
    const float bhhv = bhh[col];
    float hst[2][4] = {};
    unsigned int* my_cnt = cnt + rb * 32;

    // x-side preacts for t=0
    f32x4 ax0 = {0,0,0,0}, ax1 = {0,0,0,0};
    {
        const unsigned short* xp = xbf + ((size_t)(rb * 32 + lo)) * INF + hi * 8;
        #pragma unroll
        for (int kb = 0; kb < 16; kb++) {
            bf16x8 w = ld_bf8(wxl + kb * 1024 + lane * 16);
            ax0 = __builtin_amdgcn_mfma_f32_16x16x32_bf16(ld_bf8(xp + kb * 32), w, ax0, 0, 0, 0);
            ax1 = __builtin_amdgcn_mfma_f32_16x16x32_bf16(ld_bf8(xp + 16 * INF + kb * 32), w, ax1, 0, 0, 0);
        }
    }

    for (int t = 0; t < SEQL; t++) {
        // --- h-side preacts: pipelined chunks (8 kfrags each, issue 2 ahead) ---
        f32x4 ah0 = {0,0,0,0}, ah1 = {0,0,0,0};
        if (t > 0) {
            const unsigned short* ap = hs + (size_t)t * BH + (size_t)(rb * 32 + lo) * HID + hi * 8;
            bf16x8 A0a[8], A1a[8], Wa[8], A0b[8], A1b[8], Wb[8];
            #pragma unroll
            for (int k = 0; k < 8; k++) {            // issue chunk 0
                A0a[k] = ld_bf8c(ap + k * 32);
                A1a[k] = ld_bf8c(ap + 16 * HID + k * 32);
                Wa[k]  = ld_bf8(whl + k * 1024 + lane * 16);
            }
            #pragma unroll
            for (int k = 0; k < 8; k++) {            // issue chunk 1
                A0b[k] = ld_bf8c(ap + (8 + k) * 32);
                A1b[k] = ld_bf8c(ap + 16 * HID + (8 + k) * 32);
                Wb[k]  = ld_bf8(wxl - 32768 + (8 + k) * 1024 + lane * 16);
            }
            #pragma unroll
            for (int k = 0; k < 8; k++) {            // consume 0
                ah0 = __builtin_amdgcn_mfma_f32_16x16x32_bf16(A0a[k], Wa[k], ah0, 0, 0, 0);
                ah1 = __builtin_amdgcn_mfma_f32_16x16x32_bf16(A1a[k], Wa[k], ah1, 0, 0, 0);
            }
            #pragma unroll
            for (int k = 0; k < 8; k++) {            // issue chunk 2
                A0a[k] = ld_bf8c(ap + (16 + k) * 32);
                A1a[k] = ld_bf8c(ap + 16 * HID + (16 + k) * 32);
                Wa[k]  = ld_bf8(whl + (16 + k) * 1024 + lane * 16);
            }
            #pragma unroll
            for (int k = 0; k < 8; k++) {            // consume 1
                ah0 = __builtin_amdgcn_mfma_f32_16x16x32_bf16(A0b[k], Wb[k], ah0, 0, 0, 0);
                ah1 = __builtin_amdgcn_mfma_f32_16x16x32_bf16(A1b[k], Wb[k], ah1, 0, 0, 0);
            }
            #pragma unroll
            for (int k = 0; k < 8; k++) {            // issue chunk 3
                A0b[k] = ld_bf8c(ap + (24 + k) * 32);
                A1b[k] = ld_bf8c(ap + 16 * HID + (24 + k) * 32);
                Wb[k]  = ld_bf8(whl + (24 + k) * 1024 + lane * 16);
            }
            #pragma unroll
            for (int k = 0; k < 8; k++) {            // consume 2
                ah0 = __builtin_amdgcn_mfma_f32_16x16x32_bf16(A0a[k], Wa[k], ah0, 0, 0, 0);
                ah1 = __builtin_amdgcn_mfma_f32_16x16x32_bf16(A1a[k], Wa[k], ah1, 0, 0, 0);
            }
            #pragma unroll
            for (int k = 0; k < 8; k++) {            // consume 3
                ah0 = __builtin_amdgcn_mfma_f32_16x16x32_bf16(A0b[k], Wb[k], ah0, 0, 0, 0);
                ah1 = __builtin_amdgcn_mfma_f32_16x16x32_bf16(A1b[k], Wb[k], ah1, 0, 0, 0);
            }
        }

        // --- exchange r-pre and both hcand parts via LDS ---
        if (g == 1) {
            f32x4 v0, v1;
            #pragma unroll
            for (int r = 0; r < 4; r++) { v0[r] = ah0[r] + ax0[r] + brv; v1[r] = ah1[r] + ax1[r] + brv; }
            Px[0 * 64 + lane] = v0; Px[1 * 64 + lane] = v1;
        } else if (g == 2) {
            f32x4 v0, v1, w0, w1;
            #pragma unroll
            for (int r = 0; r < 4; r++) {
                v0[r] = ah0[r] + bhhv; v1[r] = ah1[r] + bhhv;
                w0[r] = ax0[r] + bxhv; w1[r] = ax1[r] + bxhv;
            }
            Px[2 * 64 + lane] = v0; Px[3 * 64 + lane] = v1;
            Px[4 * 64 + lane] = w0; Px[5 * 64 + lane] = w1;
        }
        __syncthreads();

        // --- finalize by wave 0; then drain own stores and arrive ---
        if (g == 0) {
            unsigned short* hdst = hs + (size_t)(t + 1) * BH;
            f32x4 az[2];
            #pragma unroll
            for (int r = 0; r < 4; r++) { az[0][r] = ah0[r] + ax0[r] + bzv; az[1][r] = ah1[r] + ax1[r] + bzv; }
            f32x4 pr[2] = { Px[0 * 64 + lane], Px[1 * 64 + lane] };
            f32x4 ph[2] = { Px[2 * 64 + lane], Px[3 * 64 + lane] };
            f32x4 px[2] = { Px[4 * 64 + lane], Px[5 * 64 + lane] };
            #pragma unroll
            for (int m = 0; m < 2; m++)
                #pragma unroll
                for (int r = 0; r < 4; r++) {
                    float z  = 1.f / (1.f + __expf(-az[m][r]));
                    float rr = 1.f / (1.f + __expf(-pr[m][r]));
                    float hc = tanhf(px[m][r] + rr * ph[m][r]);
                    hst[m][r] = (1.f - z) * hst[m][r] + z * hc;
                    st_u16c(hdst + (size_t)(rb * 32 + m * 16 + hi * 4 + r) * HID + col, f2bf(hst[m][r]));
                }
            asm volatile("s_waitcnt vmcnt(0)" ::: "memory");   // h-stores at coherence point
        }
        if (threadIdx.x == 0)
            __hip_atomic_fetch_add(my_cnt, 1u, __ATOMIC_RELAXED, __HIP_MEMORY_SCOPE_AGENT);

        // --- x-prefetch for t+1 (hidden under other WGs' finalize + propagation) ---
        f32x4 nax0 = {0,0,0,0}, nax1 = {0,0,0,0};
        if (t + 1 < SEQL) {
            const unsigned short* xp = xbf + ((size_t)(t + 1) * BATCH + rb * 32 + lo) * INF + hi * 8;
            #pragma unroll
            for (int kb = 0; kb < 16; kb++) {
                bf16x8 w = ld_bf8(wxl + kb * 1024 + lane * 16);
                nax0 = __builtin_amdgcn_mfma_f32_16x16x32_bf16(ld_bf8(xp + kb * 32), w, nax0, 0, 0, 0);
                nax1 = __builtin_amdgcn_mfma_f32_16x16x32_bf16(ld_bf8(xp + 16 * INF + kb * 32), w, nax1, 0, 0, 0);
            }
            // --- poll: every wave proceeds the moment the group is done ---
            unsigned int tgt = (unsigned int)(t + 1) * 64u;
            while (__hip_atomic_load(my_cnt, __ATOMIC_RELAXED, __HIP_MEMORY_SCOPE_AGENT) < tgt)
                __builtin_amdgcn_s_sleep(2);
        }
        ax0 = nax0; ax1 = nax1;
    }
}

// ---------------- host ----------------
extern "C" void kernel_launch(void* const* d_in, const int* in_sizes, int n_in,
                              void* d_out, int out_size, void* d_ws, size_t ws_size,
                              hipStream_t stream) {
    const float* x   = (const float*)d_in[0];
    const float* Wxz = (const float*)d_in[1];
    const float* bxz = (const float*)d_in[2];
    const float* Whz = (const float*)d_in[3];
    const float* bhz = (const float*)d_in[4];
    const float* Wxr = (const float*)d_in[5];
    const float* bxr = (const float*)d_in[6];
    const float* Whr = (const float*)d_in[7];
    const float* bhr = (const float*)d_in[8];
    const float* Wxh = (const float*)d_in[9];
    const float* bxh = (const float*)d_in[10];
    const float* Whh = (const float*)d_in[11];
    const float* bhh = (const float*)d_in[12];
    const float* Why = (const float*)d_in[13];
    const float* bhy = (const float*)d_in[14];

    char* ws = (char*)d_ws;
    size_t off = 0;
    auto alloc = [&](size_t bytes) { char* p = ws + off; off += (bytes + 255) & ~(size_t)255; return p; };
    unsigned short* Whc   = (unsigned short*)alloc((size_t)3 * HID * HID * 2);
    unsigned short* Wxc   = (unsigned short*)alloc((size_t)3 * HID * INF * 2);
    unsigned short* Whyb  = (unsigned short*)alloc((size_t)OUTF * HID * 2);
    float*          bias2 = (float*)alloc((size_t)2 * HID * 4);
    unsigned short* hsbuf = (unsigned short*)alloc((size_t)(SEQL + 1) * BATCH * HID * 2);
    unsigned int*   cnt   = (unsigned int*)alloc(256);
    unsigned short* x_bf  = (unsigned short*)d_out;  // dead until the final GEMM

    if (off > ws_size) {
        fail_sentinel<<<dim3(1), dim3(1), 0, stream>>>((float*)d_out);
        return;
    }

    auto cvt = [&](const float* s, unsigned short* d, size_t n) {
        cvt_f32_bf16<<<dim3((unsigned)((n / 4 + 255) / 256)), dim3(256), 0, stream>>>(s, d, (int)n);
    };
    cvt(x, x_bf, (size_t)SB * INF);
    cvt(Whz, Whc, (size_t)HID * HID);
    cvt(Whr, Whc + (size_t)HID * HID, (size_t)HID * HID);
    cvt(Whh, Whc + (size_t)2 * HID * HID, (size_t)HID * HID);
    cvt(Wxz, Wxc, (size_t)HID * INF);
    cvt(Wxr, Wxc + (size_t)HID * INF, (size_t)HID * INF);
    cvt(Wxh, Wxc + (size_t)2 * HID * INF, (size_t)HID * INF);
    cvt(Why, Whyb, (size_t)OUTF * HID);
    make_bias2<<<dim3(8), dim3(256), 0, stream>>>(bxz, bhz, bxr, bhr, bias2);
    (void)hipMemsetAsync(cnt, 0, 256, stream);

    gru_scan<<<dim3(128), dim3(192), 0, stream>>>(Whc, Wxc, x_bf, hsbuf, bias2, bxh, bhh, cnt);

    gemm_nt_f32<<<dim3((SB / 128) * (OUTF / 128)), dim3(256), 0, stream>>>(
        hsbuf + (size_t)BATCH * HID, HID, Whyb, HID, bhy, (float*)d_out, OUTF, HID);
}

// Round 6
// 6497.415 us; speedup vs baseline: 1.6035x; 1.2711x over previous
//
#include <hip/hip_runtime.h>
#include <hip/hip_bf16.h>

// GRU: SEQ=512, B=64, I=512, H=1024, O=512
#define SEQL 512
#define BATCH 64
#define INF 512
#define HID 1024
#define OUTF 512
#define SB (SEQL*BATCH)
#define BH (BATCH*HID)

typedef __attribute__((ext_vector_type(8))) __bf16 bf16x8;
typedef __attribute__((ext_vector_type(4))) float f32x4;

__device__ inline bf16x8 ld_bf8(const void* p) { return *reinterpret_cast<const bf16x8*>(p); }
__device__ inline unsigned short f2bf(float f) { __bf16 b = (__bf16)f; return __builtin_bit_cast(unsigned short, b); }

// Coherent 16-bit store: relaxed agent-scope atomic -> write-through to IF (sc0/sc1),
// no cache-maintenance instructions. Completion tracked by vmcnt.
__device__ inline void st_u16c(unsigned short* p, unsigned short v) {
    __hip_atomic_store(p, v, __ATOMIC_RELAXED, __HIP_MEMORY_SCOPE_AGENT);
}

// ---------------- prep kernels ----------------
__global__ void cvt_f32_bf16(const float* __restrict__ src, unsigned short* __restrict__ dst, int n) {
    int i = (blockIdx.x * blockDim.x + threadIdx.x) * 4;
    if (i < n) {
        float4 v = *reinterpret_cast<const float4*>(src + i);
        ushort4 o = make_ushort4(f2bf(v.x), f2bf(v.y), f2bf(v.z), f2bf(v.w));
        *reinterpret_cast<ushort4*>(dst + i) = o;
    }
}

__global__ void make_bias2(const float* bxz, const float* bhz, const float* bxr,
                           const float* bhr, float* bias2) {
    int i = blockIdx.x * blockDim.x + threadIdx.x;
    if (i < HID) bias2[i] = bxz[i] + bhz[i];
    else if (i < 2*HID) bias2[i] = bxr[i-HID] + bhr[i-HID];
}

__global__ void fail_sentinel(float* o) { o[0] = 1e9f; }

// ---------------- tiled NT GEMM (unchanged, validated) ----------------
__global__ __launch_bounds__(256, 2) void gemm_nt_f32(
        const unsigned short* __restrict__ A, int lda,
        const unsigned short* __restrict__ Bw, int ldb,
        const float* __restrict__ bias,
        float* __restrict__ Cf, int N, int K) {
    __shared__ __align__(16) char lds[32768];
    const int tid = threadIdx.x;
    const int ntn = N >> 7;
    const int bm = blockIdx.x / ntn, bn = blockIdx.x % ntn;
    const int rowbase = bm << 7, colbase = bn << 7;
    const int wave = tid >> 6, lane = tid & 63, lo = lane & 15, hi = lane >> 4;
    const int vm = wave >> 1, vn = wave & 1;

    auto stage = [&](int abase, int k0) {
        #pragma unroll
        for (int i = 0; i < 2; i++) {
            int linear = i * 256 + tid;
            int r = linear >> 2, s = linear & 3;
            int c = (s - (r >> 1)) & 3;
            const unsigned short* ga = A + (size_t)(rowbase + r) * lda + k0 + c * 8;
            const unsigned short* gb = Bw + (size_t)(colbase + r) * ldb + k0 + c * 8;
            __builtin_amdgcn_global_load_lds(
                (const __attribute__((address_space(1))) unsigned int*)ga,
                (__attribute__((address_space(3))) unsigned int*)(lds + abase + linear * 16), 16, 0, 0);
            __builtin_amdgcn_global_load_lds(
                (const __attribute__((address_space(1))) unsigned int*)gb,
                (__attribute__((address_space(3))) unsigned int*)(lds + 16384 + abase + linear * 16), 16, 0, 0);
        }
    };

    f32x4 acc[4][4] = {};
    const int nk = K >> 5;
    stage(0, 0);
    for (int kt = 0; kt < nk; kt++) {
        __syncthreads();
        if (kt + 1 < nk) stage(((kt + 1) & 1) * 8192, (kt + 1) << 5);
        const char* cA = lds + (kt & 1) * 8192;
        const char* cB = lds + 16384 + (kt & 1) * 8192;
        bf16x8 af[4], bfr[4];
        #pragma unroll
        for (int m = 0; m < 4; m++) {
            int r = vm * 64 + m * 16 + lo;
            af[m] = ld_bf8(cA + r * 64 + 16 * ((hi + (r >> 1)) & 3));
        }
        #pragma unroll
        for (int n = 0; n < 4; n++) {
            int r = vn * 64 + n * 16 + lo;
            bfr[n] = ld_bf8(cB + r * 64 + 16 * ((hi + (r >> 1)) & 3));
        }
        #pragma unroll
        for (int m = 0; m < 4; m++)
            #pragma unroll
            for (int n = 0; n < 4; n++)
                acc[m][n] = __builtin_amdgcn_mfma_f32_16x16x32_bf16(af[m], bfr[n], acc[m][n], 0, 0, 0);
        __syncthreads();
    }

    #pragma unroll
    for (int n = 0; n < 4; n++) {
        int col = colbase + vn * 64 + n * 16 + lo;
        float bv = bias[col];
        #pragma unroll
        for (int m = 0; m < 4; m++)
            #pragma unroll
            for (int r = 0; r < 4; r++) {
                int row = rowbase + vm * 64 + m * 16 + hi * 4 + r;
                Cf[(size_t)row * N + col] = acc[m][n][r] + bv;
            }
    }
}

// ---------------- persistent GRU scan: flag barrier (no RMWs) + L2-cached h loads ----------------
// 128 WGs x 192 threads; rb = wid>>6 (32 batch rows), cb = wid&63 (16 h-cols); wave g = gate.
// LDS: [0,144K) weight frags, [144K,150K) Px exchange. 1 WG/CU by construction.
// Sync per step (round-5 post-mortem: 64 serialized fetch_add RMWs were ~13us/step):
//   producer: wave0 finalize -> relaxed-atomic h stores (write-through IF) -> s_waitcnt vmcnt(0)
//             -> thread0 relaxed-atomic STORE flags[rb*64+cb] = t+1   (no RMW, no serialization)
//   consumer: lane l polls flags[rb*64+l] (one 256B coalesced load/iter) until __all(>= t+1),
//             then buffer_inv sc0 sc1 (invalidate L1+L2) -> PLAIN dwordx4 h loads (L2-cached:
//             ~1 IF miss per line per XCD, rest L2 hits; compiler free to pipeline).
// Safety: a wave passes poll only after its own WG's flag is set, which happens after its
// wave0 read Px -> next step's Px writes can't race (same ordering round 5 validated).
__global__ __launch_bounds__(192, 1) void gru_scan(
        const unsigned short* __restrict__ Whc,   // [3][H][H]
        const unsigned short* __restrict__ Wxc,   // [3][H][I]
        const unsigned short* __restrict__ xbf,   // [S*B][I]
        unsigned short* __restrict__ hs,          // [S+1][B][H]
        const float* __restrict__ bias2,          // [2H]
        const float* __restrict__ bxh,
        const float* __restrict__ bhh,
        unsigned int* flags) {                    // [2][64] per-WG step flags
    __shared__ __align__(16) char lds[153600];
    const int wid = blockIdx.x;
    const int rb = wid >> 6;
    const int cb = wid & 63;
    const int g = threadIdx.x / 64;
    const int lane = threadIdx.x & 63, lo = lane & 15, hi = lane >> 4;
    const int col = cb * 16 + lo;
    char* whl = lds + g * 49152;          // 32 wh frags (1 KB each)
    char* wxl = whl + 32768;              // 16 wx frags
    f32x4* Px = (f32x4*)(lds + 147456);   // 6 x 64 lanes

    // ---- stage this WG's weight slices into LDS (once) ----
    {
        const unsigned short* ph = Whc + ((size_t)g * HID + col) * HID + hi * 8;
        #pragma unroll
        for (int kb = 0; kb < 32; kb++)
            __builtin_amdgcn_global_load_lds(
                (const __attribute__((address_space(1))) unsigned int*)(ph + kb * 32),
                (__attribute__((address_space(3))) unsigned int*)(whl + kb * 1024 + lane * 16), 16, 0, 0);
        const unsigned short* pxw = Wxc + ((size_t)g * HID + col) * INF + hi * 8;
        #pragma unroll
        for (int kb = 0; kb < 16; kb++)
            __builtin_amdgcn_global_load_lds(
                (const __attribute__((address_space(1))) unsigned int*)(pxw + kb * 32),
                (__attribute__((address_space(3))) unsigned int*)(wxl + kb * 1024 + lane * 16), 16, 0, 0);
    }
    __syncthreads();

    const float bzv  = bias2[col];
    const float brv  = bias2[HID + col];
    const float bxhv = bxh[col];
    const float bhhv = bhh[col];
    float hst[2][4] = {};

    // x-side preacts for t=0
    f32x4 ax0 = {0,0,0,0}, ax1 = {0,0,0,0};
    {
        const unsigned short* xp = xbf + ((size_t)(rb * 32 + lo)) * INF + hi * 8;
        #pragma unroll
        for (int kb = 0; kb < 16; kb++) {
            bf16x8 w = ld_bf8(wxl + kb * 1024 + lane * 16);
            ax0 = __builtin_amdgcn_mfma_f32_16x16x32_bf16(ld_bf8(xp + kb * 32), w, ax0, 0, 0, 0);
            ax1 = __builtin_amdgcn_mfma_f32_16x16x32_bf16(ld_bf8(xp + 16 * INF + kb * 32), w, ax1, 0, 0, 0);
        }
    }

    for (int t = 0; t < SEQL; t++) {
        // --- h-side preacts: plain (L2-cached) loads, freshness guaranteed by the
        //     buffer_inv executed after last step's poll ---
        f32x4 ah0 = {0,0,0,0}, ah1 = {0,0,0,0};
        if (t > 0) {
            const unsigned short* ap = hs + (size_t)t * BH + (size_t)(rb * 32 + lo) * HID + hi * 8;
            #pragma unroll
            for (int kb = 0; kb < 32; kb++) {
                bf16x8 w = ld_bf8(whl + kb * 1024 + lane * 16);
                ah0 = __builtin_amdgcn_mfma_f32_16x16x32_bf16(ld_bf8(ap + kb * 32), w, ah0, 0, 0, 0);
                ah1 = __builtin_amdgcn_mfma_f32_16x16x32_bf16(ld_bf8(ap + 16 * HID + kb * 32), w, ah1, 0, 0, 0);
            }
        }

        // --- exchange r-pre and both hcand parts via LDS ---
        if (g == 1) {
            f32x4 v0, v1;
            #pragma unroll
            for (int r = 0; r < 4; r++) { v0[r] = ah0[r] + ax0[r] + brv; v1[r] = ah1[r] + ax1[r] + brv; }
            Px[0 * 64 + lane] = v0; Px[1 * 64 + lane] = v1;
        } else if (g == 2) {
            f32x4 v0, v1, w0, w1;
            #pragma unroll
            for (int r = 0; r < 4; r++) {
                v0[r] = ah0[r] + bhhv; v1[r] = ah1[r] + bhhv;
                w0[r] = ax0[r] + bxhv; w1[r] = ax1[r] + bxhv;
            }
            Px[2 * 64 + lane] = v0; Px[3 * 64 + lane] = v1;
            Px[4 * 64 + lane] = w0; Px[5 * 64 + lane] = w1;
        }
        __syncthreads();

        // --- finalize by wave 0; drain own stores; publish flag (plain store, no RMW) ---
        if (g == 0) {
            unsigned short* hdst = hs + (size_t)(t + 1) * BH;
            f32x4 az[2];
            #pragma unroll
            for (int r = 0; r < 4; r++) { az[0][r] = ah0[r] + ax0[r] + bzv; az[1][r] = ah1[r] + ax1[r] + bzv; }
            f32x4 pr[2] = { Px[0 * 64 + lane], Px[1 * 64 + lane] };
            f32x4 ph[2] = { Px[2 * 64 + lane], Px[3 * 64 + lane] };
            f32x4 px[2] = { Px[4 * 64 + lane], Px[5 * 64 + lane] };
            #pragma unroll
            for (int m = 0; m < 2; m++)
                #pragma unroll
                for (int r = 0; r < 4; r++) {
                    float z  = 1.f / (1.f + __expf(-az[m][r]));
                    float rr = 1.f / (1.f + __expf(-pr[m][r]));
                    float hc = tanhf(px[m][r] + rr * ph[m][r]);
                    hst[m][r] = (1.f - z) * hst[m][r] + z * hc;
                    st_u16c(hdst + (size_t)(rb * 32 + m * 16 + hi * 4 + r) * HID + col, f2bf(hst[m][r]));
                }
            asm volatile("s_waitcnt vmcnt(0)" ::: "memory");   // h-stores completed at the IF
        }
        if (threadIdx.x == 0)
            __hip_atomic_store(flags + rb * 64 + cb, (unsigned int)(t + 1),
                               __ATOMIC_RELAXED, __HIP_MEMORY_SCOPE_AGENT);

        // --- x-prefetch for t+1 overlaps other WGs' finalize/propagation ---
        f32x4 nax0 = {0,0,0,0}, nax1 = {0,0,0,0};
        if (t + 1 < SEQL) {
            const unsigned short* xp = xbf + ((size_t)(t + 1) * BATCH + rb * 32 + lo) * INF + hi * 8;
            #pragma unroll
            for (int kb = 0; kb < 16; kb++) {
                bf16x8 w = ld_bf8(wxl + kb * 1024 + lane * 16);
                nax0 = __builtin_amdgcn_mfma_f32_16x16x32_bf16(ld_bf8(xp + kb * 32), w, nax0, 0, 0, 0);
                nax1 = __builtin_amdgcn_mfma_f32_16x16x32_bf16(ld_bf8(xp + 16 * INF + kb * 32), w, nax1, 0, 0, 0);
            }
            // --- ballot-poll: one coalesced 256B flag read per iteration, no RMWs ---
            const unsigned int* fl = flags + rb * 64 + lane;
            unsigned int tgt = (unsigned int)(t + 1);
            while (!__all(__hip_atomic_load(fl, __ATOMIC_RELAXED, __HIP_MEMORY_SCOPE_AGENT) >= tgt))
                __builtin_amdgcn_s_sleep(1);
            // make producers' write-through h stores visible to our plain loads
            asm volatile("buffer_inv sc0 sc1" ::: "memory");
        }
        ax0 = nax0; ax1 = nax1;
    }
}

// ---------------- host ----------------
extern "C" void kernel_launch(void* const* d_in, const int* in_sizes, int n_in,
                              void* d_out, int out_size, void* d_ws, size_t ws_size,
                              hipStream_t stream) {
    const float* x   = (const float*)d_in[0];
    const float* Wxz = (const float*)d_in[1];
    const float* bxz = (const float*)d_in[2];
    const float* Whz = (const float*)d_in[3];
    const float* bhz = (const float*)d_in[4];
    const float* Wxr = (const float*)d_in[5];
    const float* bxr = (const float*)d_in[6];
    const float* Whr = (const float*)d_in[7];
    const float* bhr = (const float*)d_in[8];
    const float* Wxh = (const float*)d_in[9];
    const float* bxh = (const float*)d_in[10];
    const float* Whh = (const float*)d_in[11];
    const float* bhh = (const float*)d_in[12];
    const float* Why = (const float*)d_in[13];
    const float* bhy = (const float*)d_in[14];

    char* ws = (char*)d_ws;
    size_t off = 0;
    auto alloc = [&](size_t bytes) { char* p = ws + off; off += (bytes + 255) & ~(size_t)255; return p; };
    unsigned short* Whc   = (unsigned short*)alloc((size_t)3 * HID * HID * 2);
    unsigned short* Wxc   = (unsigned short*)alloc((size_t)3 * HID * INF * 2);
    unsigned short* Whyb  = (unsigned short*)alloc((size_t)OUTF * HID * 2);
    float*          bias2 = (float*)alloc((size_t)2 * HID * 4);
    unsigned short* hsbuf = (unsigned short*)alloc((size_t)(SEQL + 1) * BATCH * HID * 2);
    unsigned int*   flags = (unsigned int*)alloc(1024);
    unsigned short* x_bf  = (unsigned short*)d_out;  // dead until the final GEMM

    if (off > ws_size) {
        fail_sentinel<<<dim3(1), dim3(1), 0, stream>>>((float*)d_out);
        return;
    }

    auto cvt = [&](const float* s, unsigned short* d, size_t n) {
        cvt_f32_bf16<<<dim3((unsigned)((n / 4 + 255) / 256)), dim3(256), 0, stream>>>(s, d, (int)n);
    };
    cvt(x, x_bf, (size_t)SB * INF);
    cvt(Whz, Whc, (size_t)HID * HID);
    cvt(Whr, Whc + (size_t)HID * HID, (size_t)HID * HID);
    cvt(Whh, Whc + (size_t)2 * HID * HID, (size_t)HID * HID);
    cvt(Wxz, Wxc, (size_t)HID * INF);
    cvt(Wxr, Wxc + (size_t)HID * INF, (size_t)HID * INF);
    cvt(Wxh, Wxc + (size_t)2 * HID * INF, (size_t)HID * INF);
    cvt(Why, Whyb, (size_t)OUTF * HID);
    make_bias2<<<dim3(8), dim3(256), 0, stream>>>(bxz, bhz, bxr, bhr, bias2);
    (void)hipMemsetAsync(flags, 0, 1024, stream);   // reset per launch (graph-replay safe)

    gru_scan<<<dim3(128), dim3(192), 0, stream>>>(Whc, Wxc, x_bf, hsbuf, bias2, bxh, bhh, flags);

    gemm_nt_f32<<<dim3((SB / 128) * (OUTF / 128)), dim3(256), 0, stream>>>(
        hsbuf + (size_t)BATCH * HID, HID, Whyb, HID, bhy, (float*)d_out, OUTF, HID);
}

// Round 7
// 4218.004 us; speedup vs baseline: 2.4701x; 1.5404x over previous
//
#include <hip/hip_runtime.h>
#include <hip/hip_bf16.h>

// GRU: SEQ=512, B=64, I=512, H=1024, O=512
#define SEQL 512
#define BATCH 64
#define INF 512
#define HID 1024
#define OUTF 512
#define SB (SEQL*BATCH)
#define BH (BATCH*HID)

typedef __attribute__((ext_vector_type(8))) __bf16 bf16x8;
typedef __attribute__((ext_vector_type(4))) float f32x4;

__device__ inline bf16x8 ld_bf8(const void* p) { return *reinterpret_cast<const bf16x8*>(p); }
__device__ inline unsigned short f2bf(float f) { __bf16 b = (__bf16)f; return __builtin_bit_cast(unsigned short, b); }

// Coherent 16-bit store: relaxed agent-scope atomic -> write-through to IF, no cache maintenance.
__device__ inline void st_u16c(unsigned short* p, unsigned short v) {
    __hip_atomic_store(p, v, __ATOMIC_RELAXED, __HIP_MEMORY_SCOPE_AGENT);
}

// ---------------- prep kernels ----------------
__global__ void cvt_f32_bf16(const float* __restrict__ src, unsigned short* __restrict__ dst, int n) {
    int i = (blockIdx.x * blockDim.x + threadIdx.x) * 4;
    if (i < n) {
        float4 v = *reinterpret_cast<const float4*>(src + i);
        ushort4 o = make_ushort4(f2bf(v.x), f2bf(v.y), f2bf(v.z), f2bf(v.w));
        *reinterpret_cast<ushort4*>(dst + i) = o;
    }
}

__global__ void make_bias2(const float* bxz, const float* bhz, const float* bxr,
                           const float* bhr, float* bias2) {
    int i = blockIdx.x * blockDim.x + threadIdx.x;
    if (i < HID) bias2[i] = bxz[i] + bhz[i];
    else if (i < 2*HID) bias2[i] = bxr[i-HID] + bhr[i-HID];
}

__global__ void fail_sentinel(float* o) { o[0] = 1e9f; }

// ---------------- tiled NT GEMM (unchanged, validated) ----------------
__global__ __launch_bounds__(256, 2) void gemm_nt_f32(
        const unsigned short* __restrict__ A, int lda,
        const unsigned short* __restrict__ Bw, int ldb,
        const float* __restrict__ bias,
        float* __restrict__ Cf, int N, int K) {
    __shared__ __align__(16) char lds[32768];
    const int tid = threadIdx.x;
    const int ntn = N >> 7;
    const int bm = blockIdx.x / ntn, bn = blockIdx.x % ntn;
    const int rowbase = bm << 7, colbase = bn << 7;
    const int wave = tid >> 6, lane = tid & 63, lo = lane & 15, hi = lane >> 4;
    const int vm = wave >> 1, vn = wave & 1;

    auto stage = [&](int abase, int k0) {
        #pragma unroll
        for (int i = 0; i < 2; i++) {
            int linear = i * 256 + tid;
            int r = linear >> 2, s = linear & 3;
            int c = (s - (r >> 1)) & 3;
            const unsigned short* ga = A + (size_t)(rowbase + r) * lda + k0 + c * 8;
            const unsigned short* gb = Bw + (size_t)(colbase + r) * ldb + k0 + c * 8;
            __builtin_amdgcn_global_load_lds(
                (const __attribute__((address_space(1))) unsigned int*)ga,
                (__attribute__((address_space(3))) unsigned int*)(lds + abase + linear * 16), 16, 0, 0);
            __builtin_amdgcn_global_load_lds(
                (const __attribute__((address_space(1))) unsigned int*)gb,
                (__attribute__((address_space(3))) unsigned int*)(lds + 16384 + abase + linear * 16), 16, 0, 0);
        }
    };

    f32x4 acc[4][4] = {};
    const int nk = K >> 5;
    stage(0, 0);
    for (int kt = 0; kt < nk; kt++) {
        __syncthreads();
        if (kt + 1 < nk) stage(((kt + 1) & 1) * 8192, (kt + 1) << 5);
        const char* cA = lds + (kt & 1) * 8192;
        const char* cB = lds + 16384 + (kt & 1) * 8192;
        bf16x8 af[4], bfr[4];
        #pragma unroll
        for (int m = 0; m < 4; m++) {
            int r = vm * 64 + m * 16 + lo;
            af[m] = ld_bf8(cA + r * 64 + 16 * ((hi + (r >> 1)) & 3));
        }
        #pragma unroll
        for (int n = 0; n < 4; n++) {
            int r = vn * 64 + n * 16 + lo;
            bfr[n] = ld_bf8(cB + r * 64 + 16 * ((hi + (r >> 1)) & 3));
        }
        #pragma unroll
        for (int m = 0; m < 4; m++)
            #pragma unroll
            for (int n = 0; n < 4; n++)
                acc[m][n] = __builtin_amdgcn_mfma_f32_16x16x32_bf16(af[m], bfr[n], acc[m][n], 0, 0, 0);
        __syncthreads();
    }

    #pragma unroll
    for (int n = 0; n < 4; n++) {
        int col = colbase + vn * 64 + n * 16 + lo;
        float bv = bias[col];
        #pragma unroll
        for (int m = 0; m < 4; m++)
            #pragma unroll
            for (int r = 0; r < 4; r++) {
                int row = rowbase + vm * 64 + m * 16 + hi * 4 + r;
                Cf[(size_t)row * N + col] = acc[m][n][r] + bv;
            }
    }
}

// ---------------- persistent GRU scan: LDS-staged h tile, no cache invalidation ----------------
// 128 WGs x 192 threads; rb = wid>>6 (32 batch rows), cb = wid&63 (16 h-cols); wave g = gate.
// LDS (exactly 160 KB): [0,96K) wh (gate g at g*32K, frag kb at kb*1024+lane*16),
//                       [96K,160K) h tile (32 rows x 2048B) -- Px exchange ALIASES its first 6KB.
// Per step:
//   stage: all 192 threads issue ~21 global_load_lds each (aux=17 = SC0|SC1: served at the IF
//          coherence point -> NO buffer_inv needed; x/Wx stay L2-resident). Slot rotation
//          (slot+row)&127 applied on the GLOBAL source; LDS dest stays linear (G21).
//   consume: 3 waves ds_read the shared tile (each 16B frag loaded from global ONCE, not 3x).
//   sync: wave0 finalize -> write-through h stores -> vmcnt(0) -> flag store (no RMW);
//         consumers do x-prefetch for t+1 (plain loads, L2-warm) then ballot-poll 64 flags.
__global__ __launch_bounds__(192, 1) void gru_scan(
        const unsigned short* __restrict__ Whc,   // [3][H][H]
        const unsigned short* __restrict__ Wxc,   // [3][H][I]
        const unsigned short* __restrict__ xbf,   // [S*B][I]
        unsigned short* __restrict__ hs,          // [S+1][B][H]
        const float* __restrict__ bias2,          // [2H]
        const float* __restrict__ bxh,
        const float* __restrict__ bhh,
        unsigned int* flags) {                    // [2][64] per-WG step flags
    __shared__ __align__(16) char lds[163840];
    const int tid = threadIdx.x;
    const int wid = blockIdx.x;
    const int rb = wid >> 6;
    const int cb = wid & 63;
    const int g = tid / 64;
    const int lane = tid & 63, lo = lane & 15, hi = lane >> 4;
    const int col = cb * 16 + lo;
    char* whl = lds + g * 32768;          // this wave's 32 wh frags (1 KB each)
    char* hstage = lds + 98304;           // 64 KB h tile
    f32x4* Px = (f32x4*)(lds + 98304);    // aliases h tile (guarded by barriers)

    // ---- stage wh slices into LDS (once) ----
    {
        const unsigned short* ph = Whc + ((size_t)g * HID + col) * HID + hi * 8;
        #pragma unroll
        for (int kb = 0; kb < 32; kb++)
            __builtin_amdgcn_global_load_lds(
                (const __attribute__((address_space(1))) unsigned int*)(ph + kb * 32),
                (__attribute__((address_space(3))) unsigned int*)(whl + kb * 1024 + lane * 16), 16, 0, 0);
    }
    __syncthreads();

    const float bzv  = bias2[col];
    const float brv  = bias2[HID + col];
    const float bxhv = bxh[col];
    const float bhhv = bhh[col];
    float hst[2][4] = {};
    const unsigned short* wxp = Wxc + ((size_t)g * HID + col) * INF + hi * 8;

    // x-side preacts for t=0 (plain cached loads; wx re-read per step, L2-warm after step 1)
    f32x4 ax0 = {0,0,0,0}, ax1 = {0,0,0,0};
    {
        const unsigned short* xp = xbf + ((size_t)(rb * 32 + lo)) * INF + hi * 8;
        #pragma unroll
        for (int kb = 0; kb < 16; kb++) {
            bf16x8 w = ld_bf8(wxp + kb * 32);
            ax0 = __builtin_amdgcn_mfma_f32_16x16x32_bf16(ld_bf8(xp + kb * 32), w, ax0, 0, 0, 0);
            ax1 = __builtin_amdgcn_mfma_f32_16x16x32_bf16(ld_bf8(xp + 16 * INF + kb * 32), w, ax1, 0, 0, 0);
        }
    }

    for (int t = 0; t < SEQL; t++) {
        f32x4 ah0 = {0,0,0,0}, ah1 = {0,0,0,0};
        if (t > 0) {
            // --- stage h[t] tile: 4096 x 16B units, rotated source, linear LDS dest ---
            const unsigned short* hsrc = hs + (size_t)t * BH + (size_t)(rb * 32) * HID;
            for (int u = tid; u < 4096; u += 192) {
                int row = u >> 7;                       // 0..31
                int slot = ((u & 127) - row) & 127;     // inverse rotation on source
                __builtin_amdgcn_global_load_lds(
                    (const __attribute__((address_space(1))) unsigned int*)(hsrc + (size_t)row * HID + slot * 8),
                    (__attribute__((address_space(3))) unsigned int*)(hstage + u * 16), 16, 0, 17 /*SC0|SC1*/);
            }
            __syncthreads();   // drains vmcnt -> tile complete for all waves

            // --- h-side preacts from LDS (rotation-swizzled reads, uniform bank spread) ---
            #pragma unroll
            for (int kb = 0; kb < 32; kb++) {
                bf16x8 w  = ld_bf8(whl + kb * 1024 + lane * 16);
                int s0 = ((kb * 4 + hi + lo) & 127) * 16;        // row = lo
                int s1 = ((kb * 4 + hi + 16 + lo) & 127) * 16;   // row = 16+lo
                bf16x8 a0 = ld_bf8(hstage + lo * 2048 + s0);
                bf16x8 a1 = ld_bf8(hstage + (16 + lo) * 2048 + s1);
                ah0 = __builtin_amdgcn_mfma_f32_16x16x32_bf16(a0, w, ah0, 0, 0, 0);
                ah1 = __builtin_amdgcn_mfma_f32_16x16x32_bf16(a1, w, ah1, 0, 0, 0);
            }
        }
        __syncthreads();   // all waves done reading h tile -> Px alias region is free

        // --- exchange r-pre and both hcand parts via LDS ---
        if (g == 1) {
            f32x4 v0, v1;
            #pragma unroll
            for (int r = 0; r < 4; r++) { v0[r] = ah0[r] + ax0[r] + brv; v1[r] = ah1[r] + ax1[r] + brv; }
            Px[0 * 64 + lane] = v0; Px[1 * 64 + lane] = v1;
        } else if (g == 2) {
            f32x4 v0, v1, w0, w1;
            #pragma unroll
            for (int r = 0; r < 4; r++) {
                v0[r] = ah0[r] + bhhv; v1[r] = ah1[r] + bhhv;
                w0[r] = ax0[r] + bxhv; w1[r] = ax1[r] + bxhv;
            }
            Px[2 * 64 + lane] = v0; Px[3 * 64 + lane] = v1;
            Px[4 * 64 + lane] = w0; Px[5 * 64 + lane] = w1;
        }
        __syncthreads();

        // --- finalize by wave 0; drain own stores; publish flag (plain store, no RMW) ---
        if (g == 0) {
            unsigned short* hdst = hs + (size_t)(t + 1) * BH;
            f32x4 az[2];
            #pragma unroll
            for (int r = 0; r < 4; r++) { az[0][r] = ah0[r] + ax0[r] + bzv; az[1][r] = ah1[r] + ax1[r] + bzv; }
            f32x4 pr[2] = { Px[0 * 64 + lane], Px[1 * 64 + lane] };
            f32x4 ph[2] = { Px[2 * 64 + lane], Px[3 * 64 + lane] };
            f32x4 px[2] = { Px[4 * 64 + lane], Px[5 * 64 + lane] };
            #pragma unroll
            for (int m = 0; m < 2; m++)
                #pragma unroll
                for (int r = 0; r < 4; r++) {
                    float z  = 1.f / (1.f + __expf(-az[m][r]));
                    float rr = 1.f / (1.f + __expf(-pr[m][r]));
                    float hc = tanhf(px[m][r] + rr * ph[m][r]);
                    hst[m][r] = (1.f - z) * hst[m][r] + z * hc;
                    st_u16c(hdst + (size_t)(rb * 32 + m * 16 + hi * 4 + r) * HID + col, f2bf(hst[m][r]));
                }
            asm volatile("s_waitcnt vmcnt(0)" ::: "memory");   // h-stores completed at the IF
        }
        if (tid == 0)
            __hip_atomic_store(flags + rb * 64 + cb, (unsigned int)(t + 1),
                               __ATOMIC_RELAXED, __HIP_MEMORY_SCOPE_AGENT);

        // --- x-prefetch for t+1 (L2-warm plain loads) overlaps flag propagation ---
        f32x4 nax0 = {0,0,0,0}, nax1 = {0,0,0,0};
        if (t + 1 < SEQL) {
            const unsigned short* xp = xbf + ((size_t)(t + 1) * BATCH + rb * 32 + lo) * INF + hi * 8;
            #pragma unroll
            for (int kb = 0; kb < 16; kb++) {
                bf16x8 w = ld_bf8(wxp + kb * 32);
                nax0 = __builtin_amdgcn_mfma_f32_16x16x32_bf16(ld_bf8(xp + kb * 32), w, nax0, 0, 0, 0);
                nax1 = __builtin_amdgcn_mfma_f32_16x16x32_bf16(ld_bf8(xp + 16 * INF + kb * 32), w, nax1, 0, 0, 0);
            }
            // --- ballot-poll: one coalesced 256B bypass read per iteration ---
            const unsigned int* fl = flags + rb * 64 + lane;
            unsigned int tgt = (unsigned int)(t + 1);
            while (!__all(__hip_atomic_load(fl, __ATOMIC_RELAXED, __HIP_MEMORY_SCOPE_AGENT) >= tgt))
                __builtin_amdgcn_s_sleep(1);
        }
        ax0 = nax0; ax1 = nax1;
    }
}

// ---------------- host ----------------
extern "C" void kernel_launch(void* const* d_in, const int* in_sizes, int n_in,
                              void* d_out, int out_size, void* d_ws, size_t ws_size,
                              hipStream_t stream) {
    const float* x   = (const float*)d_in[0];
    const float* Wxz = (const float*)d_in[1];
    const float* bxz = (const float*)d_in[2];
    const float* Whz = (const float*)d_in[3];
    const float* bhz = (const float*)d_in[4];
    const float* Wxr = (const float*)d_in[5];
    const float* bxr = (const float*)d_in[6];
    const float* Whr = (const float*)d_in[7];
    const float* bhr = (const float*)d_in[8];
    const float* Wxh = (const float*)d_in[9];
    const float* bxh = (const float*)d_in[10];
    const float* Whh = (const float*)d_in[11];
    const float* bhh = (const float*)d_in[12];
    const float* Why = (const float*)d_in[13];
    const float* bhy = (const float*)d_in[14];

    char* ws = (char*)d_ws;
    size_t off = 0;
    auto alloc = [&](size_t bytes) { char* p = ws + off; off += (bytes + 255) & ~(size_t)255; return p; };
    unsigned short* Whc   = (unsigned short*)alloc((size_t)3 * HID * HID * 2);
    unsigned short* Wxc   = (unsigned short*)alloc((size_t)3 * HID * INF * 2);
    unsigned short* Whyb  = (unsigned short*)alloc((size_t)OUTF * HID * 2);
    float*          bias2 = (float*)alloc((size_t)2 * HID * 4);
    unsigned short* hsbuf = (unsigned short*)alloc((size_t)(SEQL + 1) * BATCH * HID * 2);
    unsigned int*   flags = (unsigned int*)alloc(1024);
    unsigned short* x_bf  = (unsigned short*)d_out;  // dead until the final GEMM

    if (off > ws_size) {
        fail_sentinel<<<dim3(1), dim3(1), 0, stream>>>((float*)d_out);
        return;
    }

    auto cvt = [&](const float* s, unsigned short* d, size_t n) {
        cvt_f32_bf16<<<dim3((unsigned)((n / 4 + 255) / 256)), dim3(256), 0, stream>>>(s, d, (int)n);
    };
    cvt(x, x_bf, (size_t)SB * INF);
    cvt(Whz, Whc, (size_t)HID * HID);
    cvt(Whr, Whc + (size_t)HID * HID, (size_t)HID * HID);
    cvt(Whh, Whc + (size_t)2 * HID * HID, (size_t)HID * HID);
    cvt(Wxz, Wxc, (size_t)HID * INF);
    cvt(Wxr, Wxc + (size_t)HID * INF, (size_t)HID * INF);
    cvt(Wxh, Wxc + (size_t)2 * HID * INF, (size_t)HID * INF);
    cvt(Why, Whyb, (size_t)OUTF * HID);
    make_bias2<<<dim3(8), dim3(256), 0, stream>>>(bxz, bhz, bxr, bhr, bias2);
    (void)hipMemsetAsync(flags, 0, 1024, stream);   // reset per launch (graph-replay safe)

    gru_scan<<<dim3(128), dim3(192), 0, stream>>>(Whc, Wxc, x_bf, hsbuf, bias2, bxh, bhh, flags);

    gemm_nt_f32<<<dim3((SB / 128) * (OUTF / 128)), dim3(256), 0, stream>>>(
        hsbuf + (size_t)BATCH * HID, HID, Whyb, HID, bhy, (float*)d_out, OUTF, HID);
}

// Round 8
// 3344.779 us; speedup vs baseline: 3.1150x; 1.2611x over previous
//
#include <hip/hip_runtime.h>
#include <hip/hip_bf16.h>

// GRU: SEQ=512, B=64, I=512, H=1024, O=512
#define SEQL 512
#define BATCH 64
#define INF 512
#define HID 1024
#define OUTF 512
#define SB (SEQL*BATCH)
#define BH (BATCH*HID)

typedef __attribute__((ext_vector_type(8))) __bf16 bf16x8;
typedef __attribute__((ext_vector_type(4))) float f32x4;

__device__ inline bf16x8 ld_bf8(const void* p) { return *reinterpret_cast<const bf16x8*>(p); }
__device__ inline unsigned short f2bf(float f) { __bf16 b = (__bf16)f; return __builtin_bit_cast(unsigned short, b); }

// Coherent 8B store: relaxed agent-scope atomic -> write-through to IF, no cache maintenance.
__device__ inline void st_u64c(void* p, unsigned long long v) {
    __hip_atomic_store((unsigned long long*)p, v, __ATOMIC_RELAXED, __HIP_MEMORY_SCOPE_AGENT);
}

// ---------------- prep kernels ----------------
__global__ void cvt_f32_bf16(const float* __restrict__ src, unsigned short* __restrict__ dst, int n) {
    int i = (blockIdx.x * blockDim.x + threadIdx.x) * 4;
    if (i < n) {
        float4 v = *reinterpret_cast<const float4*>(src + i);
        ushort4 o = make_ushort4(f2bf(v.x), f2bf(v.y), f2bf(v.z), f2bf(v.w));
        *reinterpret_cast<ushort4*>(dst + i) = o;
    }
}

__global__ void make_bias2(const float* bxz, const float* bhz, const float* bxr,
                           const float* bhr, float* bias2) {
    int i = blockIdx.x * blockDim.x + threadIdx.x;
    if (i < HID) bias2[i] = bxz[i] + bhz[i];
    else if (i < 2*HID) bias2[i] = bxr[i-HID] + bhr[i-HID];
}

__global__ void fail_sentinel(float* o) { o[0] = 1e9f; }

// ---------------- tiled NT GEMM (unchanged, validated) ----------------
__global__ __launch_bounds__(256, 2) void gemm_nt_f32(
        const unsigned short* __restrict__ A, int lda,
        const unsigned short* __restrict__ Bw, int ldb,
        const float* __restrict__ bias,
        float* __restrict__ Cf, int N, int K) {
    __shared__ __align__(16) char lds[32768];
    const int tid = threadIdx.x;
    const int ntn = N >> 7;
    const int bm = blockIdx.x / ntn, bn = blockIdx.x % ntn;
    const int rowbase = bm << 7, colbase = bn << 7;
    const int wave = tid >> 6, lane = tid & 63, lo = lane & 15, hi = lane >> 4;
    const int vm = wave >> 1, vn = wave & 1;

    auto stage = [&](int abase, int k0) {
        #pragma unroll
        for (int i = 0; i < 2; i++) {
            int linear = i * 256 + tid;
            int r = linear >> 2, s = linear & 3;
            int c = (s - (r >> 1)) & 3;
            const unsigned short* ga = A + (size_t)(rowbase + r) * lda + k0 + c * 8;
            const unsigned short* gb = Bw + (size_t)(colbase + r) * ldb + k0 + c * 8;
            __builtin_amdgcn_global_load_lds(
                (const __attribute__((address_space(1))) unsigned int*)ga,
                (__attribute__((address_space(3))) unsigned int*)(lds + abase + linear * 16), 16, 0, 0);
            __builtin_amdgcn_global_load_lds(
                (const __attribute__((address_space(1))) unsigned int*)gb,
                (__attribute__((address_space(3))) unsigned int*)(lds + 16384 + abase + linear * 16), 16, 0, 0);
        }
    };

    f32x4 acc[4][4] = {};
    const int nk = K >> 5;
    stage(0, 0);
    for (int kt = 0; kt < nk; kt++) {
        __syncthreads();
        if (kt + 1 < nk) stage(((kt + 1) & 1) * 8192, (kt + 1) << 5);
        const char* cA = lds + (kt & 1) * 8192;
        const char* cB = lds + 16384 + (kt & 1) * 8192;
        bf16x8 af[4], bfr[4];
        #pragma unroll
        for (int m = 0; m < 4; m++) {
            int r = vm * 64 + m * 16 + lo;
            af[m] = ld_bf8(cA + r * 64 + 16 * ((hi + (r >> 1)) & 3));
        }
        #pragma unroll
        for (int n = 0; n < 4; n++) {
            int r = vn * 64 + n * 16 + lo;
            bfr[n] = ld_bf8(cB + r * 64 + 16 * ((hi + (r >> 1)) & 3));
        }
        #pragma unroll
        for (int m = 0; m < 4; m++)
            #pragma unroll
            for (int n = 0; n < 4; n++)
                acc[m][n] = __builtin_amdgcn_mfma_f32_16x16x32_bf16(af[m], bfr[n], acc[m][n], 0, 0, 0);
        __syncthreads();
    }

    #pragma unroll
    for (int n = 0; n < 4; n++) {
        int col = colbase + vn * 64 + n * 16 + lo;
        float bv = bias[col];
        #pragma unroll
        for (int m = 0; m < 4; m++)
            #pragma unroll
            for (int r = 0; r < 4; r++) {
                int row = rowbase + vm * 64 + m * 16 + hi * 4 + r;
                Cf[(size_t)row * N + col] = acc[m][n][r] + bv;
            }
    }
}

// ---------------- persistent GRU scan v4: 256 WGs, fragment-major h tile ----------------
// 256 WGs x 192 threads; rb = wid>>6 in 0..3 (16 batch rows -> 4 INDEPENDENT scan groups),
// cb = wid&63 (16 h-cols); wave g = gate {z,r,hcand}.
// LDS: [0,96K) wh; [96K,128K) h tile; [128K,131K) Px; [131K,131.5K) T repack. No aliasing.
// h tile is FRAGMENT-MAJOR (round-7 post-mortem: row-major + rotation = 5e7 bank conflicts):
//   LDS 16B unit v = kb*64 + lane holds global chunk (row = v&15, slot = v>>4), so the
//   consume read is hstage + kb*1024 + lane*16 -- identical pattern to wh (measured 0-conflict).
//   The permutation lives in the STAGE's global source address (linear LDS dest, G21).
// Sync: producer wave0 repacks h through T -> ONE coalesced 8B agent-scope store per lane ->
//   vmcnt(0) -> flag store (no RMW). Consumers: nax prefetch overlaps skew -> ballot-poll 64 flags.
__global__ __launch_bounds__(192, 1) void gru_scan(
        const unsigned short* __restrict__ Whc,   // [3][H][H]
        const unsigned short* __restrict__ Wxc,   // [3][H][I]
        const unsigned short* __restrict__ xbf,   // [S*B][I]
        unsigned short* __restrict__ hs,          // [S+1][B][H]
        const float* __restrict__ bias2,          // [2H]
        const float* __restrict__ bxh,
        const float* __restrict__ bhh,
        unsigned int* flags) {                    // [4][64] per-WG step flags
    __shared__ __align__(16) char lds[134656];
    const int tid = threadIdx.x;
    const int wid = blockIdx.x;
    const int rb = wid >> 6;          // 0..3
    const int cb = wid & 63;
    const int g = tid / 64;
    const int lane = tid & 63, lo = lane & 15, hi = lane >> 4;
    const int col = cb * 16 + lo;
    char* whl = lds + g * 32768;                       // this wave's 32 wh frags
    char* hstage = lds + 98304;                        // 32 KB fragment-major h tile
    f32x4* Px = (f32x4*)(lds + 131072);                // 3 KB exchange
    unsigned short* T = (unsigned short*)(lds + 134144); // 512 B store-repack

    // ---- stage wh slices into LDS (once) ----
    {
        const unsigned short* ph = Whc + ((size_t)g * HID + col) * HID + hi * 8;
        #pragma unroll
        for (int kb = 0; kb < 32; kb++)
            __builtin_amdgcn_global_load_lds(
                (const __attribute__((address_space(1))) unsigned int*)(ph + kb * 32),
                (__attribute__((address_space(3))) unsigned int*)(whl + kb * 1024 + lane * 16), 16, 0, 0);
    }
    __syncthreads();

    const float bzv  = bias2[col];
    const float brv  = bias2[HID + col];
    const float bxhv = bxh[col];
    const float bhhv = bhh[col];
    float hst[4] = {0.f, 0.f, 0.f, 0.f};   // fp32 state: row = rb*16 + hi*4 + r, col
    const unsigned short* wxp = Wxc + ((size_t)g * HID + col) * INF + hi * 8;

    // x-side preacts for t=0
    f32x4 ax = {0,0,0,0};
    {
        const unsigned short* xp = xbf + ((size_t)(rb * 16 + lo)) * INF + hi * 8;
        #pragma unroll
        for (int kb = 0; kb < 16; kb++)
            ax = __builtin_amdgcn_mfma_f32_16x16x32_bf16(ld_bf8(xp + kb * 32), ld_bf8(wxp + kb * 32), ax, 0, 0, 0);
    }

    for (int t = 0; t < SEQL; t++) {
        // --- stage h[t] tile (poll for it happened at the end of the previous iteration) ---
        if (t > 0) {
            const unsigned short* hsrc = hs + (size_t)t * BH + (size_t)(rb * 16) * HID;
            #pragma unroll
            for (int it = 0; it < 10; it++) {
                int v = it * 192 + tid;               // LDS unit v = kb*64+lane
                __builtin_amdgcn_global_load_lds(
                    (const __attribute__((address_space(1))) unsigned int*)(hsrc + (size_t)(v & 15) * HID + (v >> 4) * 8),
                    (__attribute__((address_space(3))) unsigned int*)(hstage + v * 16), 16, 0, 17 /*SC0|SC1*/);
            }
            if (tid < 128) {                          // remaining 128 units (waves 0,1 full)
                int v = 1920 + tid;
                __builtin_amdgcn_global_load_lds(
                    (const __attribute__((address_space(1))) unsigned int*)(hsrc + (size_t)(v & 15) * HID + (v >> 4) * 8),
                    (__attribute__((address_space(3))) unsigned int*)(hstage + v * 16), 16, 0, 17);
            }
        }
        __syncthreads();   // stage landed (each wave drains own vmcnt before s_barrier)

        // --- h-side preacts: conflict-free lane-linear LDS reads ---
        f32x4 ah = {0,0,0,0};
        if (t > 0) {
            #pragma unroll
            for (int kb = 0; kb < 32; kb++) {
                bf16x8 w = ld_bf8(whl + kb * 1024 + lane * 16);
                bf16x8 a = ld_bf8(hstage + kb * 1024 + lane * 16);
                ah = __builtin_amdgcn_mfma_f32_16x16x32_bf16(a, w, ah, 0, 0, 0);
            }
        }

        // --- exchange r-pre and both hcand parts via LDS ---
        if (g == 1) {
            f32x4 v;
            #pragma unroll
            for (int r = 0; r < 4; r++) v[r] = ah[r] + ax[r] + brv;
            Px[0 * 64 + lane] = v;
        } else if (g == 2) {
            f32x4 v, w;
            #pragma unroll
            for (int r = 0; r < 4; r++) { v[r] = ah[r] + bhhv; w[r] = ax[r] + bxhv; }
            Px[1 * 64 + lane] = v;
            Px[2 * 64 + lane] = w;
        }
        __syncthreads();

        // --- finalize by wave 0: gates -> new h -> T-repack -> ONE 8B coherent store/lane ---
        if (g == 0) {
            unsigned short* hdst = hs + (size_t)(t + 1) * BH;
            f32x4 pr = Px[0 * 64 + lane];
            f32x4 ph_ = Px[1 * 64 + lane];
            f32x4 px_ = Px[2 * 64 + lane];
            #pragma unroll
            for (int r = 0; r < 4; r++) {
                float z  = 1.f / (1.f + __expf(-(ah[r] + ax[r] + bzv)));
                float rr = 1.f / (1.f + __expf(-pr[r]));
                float hc = tanhf(px_[r] + rr * ph_[r]);
                hst[r] = (1.f - z) * hst[r] + z * hc;
                T[(hi * 4 + r) * 16 + lo] = f2bf(hst[r]);   // T[row16][col16]
            }
            asm volatile("s_waitcnt lgkmcnt(0)" ::: "memory");  // cross-lane T writes complete
            int row = lane >> 2, q = lane & 3;
            unsigned long long val = *(const unsigned long long*)(T + row * 16 + q * 4);
            st_u64c(hdst + (size_t)(rb * 16 + row) * HID + cb * 16 + q * 4, val);
            asm volatile("s_waitcnt vmcnt(0)" ::: "memory");    // h-store at the IF
        }
        if (tid == 0)
            __hip_atomic_store(flags + rb * 64 + cb, (unsigned int)(t + 1),
                               __ATOMIC_RELAXED, __HIP_MEMORY_SCOPE_AGENT);

        // --- x-prefetch for t+1 (L2-warm) overlaps flag propagation; then ballot-poll ---
        f32x4 nax = {0,0,0,0};
        if (t + 1 < SEQL) {
            const unsigned short* xp = xbf + ((size_t)(t + 1) * BATCH + rb * 16 + lo) * INF + hi * 8;
            #pragma unroll
            for (int kb = 0; kb < 16; kb++)
                nax = __builtin_amdgcn_mfma_f32_16x16x32_bf16(ld_bf8(xp + kb * 32), ld_bf8(wxp + kb * 32), nax, 0, 0, 0);
            const unsigned int* fl = flags + rb * 64 + lane;
            unsigned int tgt = (unsigned int)(t + 1);
            while (!__all(__hip_atomic_load(fl, __ATOMIC_RELAXED, __HIP_MEMORY_SCOPE_AGENT) >= tgt))
                __builtin_amdgcn_s_sleep(1);
        }
        ax = nax;
    }
}

// ---------------- host ----------------
extern "C" void kernel_launch(void* const* d_in, const int* in_sizes, int n_in,
                              void* d_out, int out_size, void* d_ws, size_t ws_size,
                              hipStream_t stream) {
    const float* x   = (const float*)d_in[0];
    const float* Wxz = (const float*)d_in[1];
    const float* bxz = (const float*)d_in[2];
    const float* Whz = (const float*)d_in[3];
    const float* bhz = (const float*)d_in[4];
    const float* Wxr = (const float*)d_in[5];
    const float* bxr = (const float*)d_in[6];
    const float* Whr = (const float*)d_in[7];
    const float* bhr = (const float*)d_in[8];
    const float* Wxh = (const float*)d_in[9];
    const float* bxh = (const float*)d_in[10];
    const float* Whh = (const float*)d_in[11];
    const float* bhh = (const float*)d_in[12];
    const float* Why = (const float*)d_in[13];
    const float* bhy = (const float*)d_in[14];

    char* ws = (char*)d_ws;
    size_t off = 0;
    auto alloc = [&](size_t bytes) { char* p = ws + off; off += (bytes + 255) & ~(size_t)255; return p; };
    unsigned short* Whc   = (unsigned short*)alloc((size_t)3 * HID * HID * 2);
    unsigned short* Wxc   = (unsigned short*)alloc((size_t)3 * HID * INF * 2);
    unsigned short* Whyb  = (unsigned short*)alloc((size_t)OUTF * HID * 2);
    float*          bias2 = (float*)alloc((size_t)2 * HID * 4);
    unsigned short* hsbuf = (unsigned short*)alloc((size_t)(SEQL + 1) * BATCH * HID * 2);
    unsigned int*   flags = (unsigned int*)alloc(1024);
    unsigned short* x_bf  = (unsigned short*)d_out;  // dead until the final GEMM

    if (off > ws_size) {
        fail_sentinel<<<dim3(1), dim3(1), 0, stream>>>((float*)d_out);
        return;
    }

    auto cvt = [&](const float* s, unsigned short* d, size_t n) {
        cvt_f32_bf16<<<dim3((unsigned)((n / 4 + 255) / 256)), dim3(256), 0, stream>>>(s, d, (int)n);
    };
    cvt(x, x_bf, (size_t)SB * INF);
    cvt(Whz, Whc, (size_t)HID * HID);
    cvt(Whr, Whc + (size_t)HID * HID, (size_t)HID * HID);
    cvt(Whh, Whc + (size_t)2 * HID * HID, (size_t)HID * HID);
    cvt(Wxz, Wxc, (size_t)HID * INF);
    cvt(Wxr, Wxc + (size_t)HID * INF, (size_t)HID * INF);
    cvt(Wxh, Wxc + (size_t)2 * HID * INF, (size_t)HID * INF);
    cvt(Why, Whyb, (size_t)OUTF * HID);
    make_bias2<<<dim3(8), dim3(256), 0, stream>>>(bxz, bhz, bxr, bhr, bias2);
    (void)hipMemsetAsync(flags, 0, 1024, stream);   // reset per launch (graph-replay safe)

    gru_scan<<<dim3(256), dim3(192), 0, stream>>>(Whc, Wxc, x_bf, hsbuf, bias2, bxh, bhh, flags);

    gemm_nt_f32<<<dim3((SB / 128) * (OUTF / 128)), dim3(256), 0, stream>>>(
        hsbuf + (size_t)BATCH * HID, HID, Whyb, HID, bhy, (float*)d_out, OUTF, HID);
}